// Round 1
// baseline (868.452 us; speedup 1.0000x reference)
//
#include <hip/hip_runtime.h>
#include <math.h>

#define B_ 2
#define N_ 2048
#define D_ 1024
#define H_ 16
#define DH_ 64
#define ROWS (B_*N_)      // 4096
#define FOURD (4*D_)      // 4096
#define EPS_ 1e-5f

// ---------------------------------------------------------------------------
// Tiled fp32 SGEMM, C[M,N] = A[M,K] * Bw[N,K]^T + bias, optional silu on
// columns < siluLim (fuses the silu(q), silu(k) from the reference).
// 128x128 tile, 256 threads, 8x8 micro-tile per thread, KT=16.
// ---------------------------------------------------------------------------
__global__ __launch_bounds__(256)
void gemm_nt(const float* __restrict__ A, const float* __restrict__ Bw,
             const float* __restrict__ bias, float* __restrict__ C,
             int M, int N, int K, int siluLim)
{
    __shared__ float As[16][128];
    __shared__ float Bs[16][128];

    const int tid = threadIdx.x;
    const int lr  = tid & 127;      // row within tile for staging
    const int lh  = tid >> 7;       // 0/1 -> k offset 0 or 8
    const int tx  = tid & 15;       // micro-tile col group
    const int ty  = tid >> 4;       // micro-tile row group
    const int row0 = blockIdx.y * 128;
    const int col0 = blockIdx.x * 128;

    float acc[8][8];
#pragma unroll
    for (int i = 0; i < 8; ++i)
#pragma unroll
        for (int j = 0; j < 8; ++j) acc[i][j] = 0.f;

    const float* ap = A  + (size_t)(row0 + lr) * K + lh * 8;
    const float* bp = Bw + (size_t)(col0 + lr) * K + lh * 8;

    for (int k0 = 0; k0 < K; k0 += 16) {
        float4 a0 = *(const float4*)(ap);
        float4 a1 = *(const float4*)(ap + 4);
        float4 b0 = *(const float4*)(bp);
        float4 b1 = *(const float4*)(bp + 4);
        const int kk = lh * 8;
        As[kk+0][lr] = a0.x; As[kk+1][lr] = a0.y; As[kk+2][lr] = a0.z; As[kk+3][lr] = a0.w;
        As[kk+4][lr] = a1.x; As[kk+5][lr] = a1.y; As[kk+6][lr] = a1.z; As[kk+7][lr] = a1.w;
        Bs[kk+0][lr] = b0.x; Bs[kk+1][lr] = b0.y; Bs[kk+2][lr] = b0.z; Bs[kk+3][lr] = b0.w;
        Bs[kk+4][lr] = b1.x; Bs[kk+5][lr] = b1.y; Bs[kk+6][lr] = b1.z; Bs[kk+7][lr] = b1.w;
        __syncthreads();

#pragma unroll
        for (int kt = 0; kt < 16; ++kt) {
            float4 av0 = *(const float4*)&As[kt][ty*8];
            float4 av1 = *(const float4*)&As[kt][ty*8 + 4];
            float4 bv0 = *(const float4*)&Bs[kt][tx*8];
            float4 bv1 = *(const float4*)&Bs[kt][tx*8 + 4];
            float a[8] = {av0.x, av0.y, av0.z, av0.w, av1.x, av1.y, av1.z, av1.w};
            float b[8] = {bv0.x, bv0.y, bv0.z, bv0.w, bv1.x, bv1.y, bv1.z, bv1.w};
#pragma unroll
            for (int i = 0; i < 8; ++i)
#pragma unroll
                for (int j = 0; j < 8; ++j)
                    acc[i][j] = fmaf(a[i], b[j], acc[i][j]);
        }
        __syncthreads();
        ap += 16; bp += 16;
    }

#pragma unroll
    for (int i = 0; i < 8; ++i) {
        const int r = row0 + ty * 8 + i;
#pragma unroll
        for (int j = 0; j < 8; ++j) {
            const int c = col0 + tx * 8 + j;
            float v = acc[i][j] + bias[c];
            if (c < siluLim) v = v / (1.f + expf(-v));   // silu
            C[(size_t)r * N + c] = v;
        }
    }
}

// ---------------------------------------------------------------------------
// KV[b,h,d,e] = sum_n lrpe(k)[n,d] * v[n,e];  d in [0,128), e in [0,64).
// lrpe(k)[n,d] = k[n,d&63] * (d<64 ? cos : sin)(theta[h,d&63]*n), k pre-silu'd.
// One block per (b,h,chunk of 256 n), fp32 atomic accumulation.
// ---------------------------------------------------------------------------
__global__ __launch_bounds__(256)
void kv_kernel(const float* __restrict__ qkvu, const float* __restrict__ theta,
               float* __restrict__ kv)
{
    __shared__ float kl_s[64][128];
    __shared__ float v_s[64][64];

    const int bid   = blockIdx.x;
    const int chunk = bid & 7;          // 8 chunks of 256 n
    const int h     = (bid >> 3) & 15;
    const int b     = bid >> 7;
    const int tid   = threadIdx.x;
    const int tr    = tid >> 4;         // 0..15 -> rows tr*8..+7 of 128
    const int tc    = tid & 15;         // 0..15 -> cols tc*4..+3 of 64

    float acc[8][4];
#pragma unroll
    for (int i = 0; i < 8; ++i)
#pragma unroll
        for (int j = 0; j < 4; ++j) acc[i][j] = 0.f;

    const int n0 = chunk * 256;
    for (int sub = 0; sub < 4; ++sub) {
        const int nbase = n0 + sub * 64;
        // stage lrpe(k): 64 n x 128 d
        for (int idx = tid; idx < 64 * 128; idx += 256) {
            const int nn = idx >> 7, d = idx & 127, dh = d & 63;
            const int n = nbase + nn;
            const float kval = qkvu[(size_t)(b * N_ + n) * FOURD + D_ + h * DH_ + dh];
            const float th = theta[h * DH_ + dh] * (float)n;
            float s, c; sincosf(th, &s, &c);
            kl_s[nn][d] = kval * ((d < 64) ? c : s);
        }
        // stage v: 64 n x 64 e
        for (int idx = tid; idx < 64 * 64; idx += 256) {
            const int nn = idx >> 6, e = idx & 63;
            const int n = nbase + nn;
            v_s[nn][e] = qkvu[(size_t)(b * N_ + n) * FOURD + 2 * D_ + h * DH_ + e];
        }
        __syncthreads();

        for (int nn = 0; nn < 64; ++nn) {
            float4 x0 = *(const float4*)&kl_s[nn][tr*8];
            float4 x1 = *(const float4*)&kl_s[nn][tr*8 + 4];
            float4 y  = *(const float4*)&v_s[nn][tc*4];
            float a[8] = {x0.x, x0.y, x0.z, x0.w, x1.x, x1.y, x1.z, x1.w};
            float vv[4] = {y.x, y.y, y.z, y.w};
#pragma unroll
            for (int i = 0; i < 8; ++i)
#pragma unroll
                for (int j = 0; j < 4; ++j)
                    acc[i][j] = fmaf(a[i], vv[j], acc[i][j]);
        }
        __syncthreads();
    }

    float* kvb = kv + (size_t)(b * H_ + h) * 128 * 64;
#pragma unroll
    for (int i = 0; i < 8; ++i)
#pragma unroll
        for (int j = 0; j < 4; ++j)
            atomicAdd(&kvb[(tr * 8 + i) * 64 + tc * 4 + j], acc[i][j]);
}

// ---------------------------------------------------------------------------
// o[row,c] = sum_d qc[c_h,d]*KV[d,e] + qs[c_h,d]*KV[64+d,e]; then LayerNorm
// over D=1024, * ln_w + ln_b, * u. One block (256 thr) per row, 4 cols/thread.
// ---------------------------------------------------------------------------
__global__ __launch_bounds__(256)
void attn_ln_kernel(const float* __restrict__ qkvu, const float* __restrict__ kv,
                    const float* __restrict__ theta, const float* __restrict__ ln_w,
                    const float* __restrict__ ln_b, float* __restrict__ g)
{
    __shared__ float qc_s[1024];
    __shared__ float qs_s[1024];
    __shared__ float red[16];

    const int row = blockIdx.x;          // b*N + n
    const int b   = row >> 11;           // N_ = 2048
    const int n   = row & (N_ - 1);
    const int tid = threadIdx.x;
    const int c0  = tid * 4;

    {   // stage q*cos / q*sin (q already silu'd by gemm1 epilogue)
        float4 qv = *(const float4*)&qkvu[(size_t)row * FOURD + c0];
        float q[4] = {qv.x, qv.y, qv.z, qv.w};
#pragma unroll
        for (int j = 0; j < 4; ++j) {
            const int c = c0 + j;
            const float th = theta[c] * (float)n;   // theta flat idx == h*64+dh == c
            float s, cc; sincosf(th, &s, &cc);
            qc_s[c] = q[j] * cc;
            qs_s[c] = q[j] * s;
        }
    }
    __syncthreads();

    const int h  = c0 >> 6;
    const int e0 = c0 & 63;
    const float* kvb = kv + (size_t)(b * H_ + h) * 8192;
    float o[4] = {0.f, 0.f, 0.f, 0.f};
    for (int d = 0; d < 64; ++d) {
        const float qc = qc_s[h * 64 + d];
        const float qs = qs_s[h * 64 + d];
        float4 kc = *(const float4*)&kvb[d * 64 + e0];
        float4 ks = *(const float4*)&kvb[(64 + d) * 64 + e0];
        o[0] = fmaf(qc, kc.x, fmaf(qs, ks.x, o[0]));
        o[1] = fmaf(qc, kc.y, fmaf(qs, ks.y, o[1]));
        o[2] = fmaf(qc, kc.z, fmaf(qs, ks.z, o[2]));
        o[3] = fmaf(qc, kc.w, fmaf(qs, ks.w, o[3]));
    }

    // LayerNorm reduction over 1024 cols
    float sum = o[0] + o[1] + o[2] + o[3];
    float sq  = o[0]*o[0] + o[1]*o[1] + o[2]*o[2] + o[3]*o[3];
#pragma unroll
    for (int off = 32; off; off >>= 1) {
        sum += __shfl_down(sum, off, 64);
        sq  += __shfl_down(sq,  off, 64);
    }
    const int wave = tid >> 6;
    if ((tid & 63) == 0) { red[wave] = sum; red[4 + wave] = sq; }
    __syncthreads();
    if (tid == 0) {
        const float s  = red[0] + red[1] + red[2] + red[3];
        const float q2 = red[4] + red[5] + red[6] + red[7];
        const float mu = s * (1.f / (float)D_);
        const float var = q2 * (1.f / (float)D_) - mu * mu;
        red[8] = mu;
        red[9] = rsqrtf(var + EPS_);
    }
    __syncthreads();
    const float mu = red[8], rs = red[9];

    float4 uv = *(const float4*)&qkvu[(size_t)row * FOURD + 3 * D_ + c0];
    float4 wv = *(const float4*)&ln_w[c0];
    float4 bv = *(const float4*)&ln_b[c0];
    float u[4] = {uv.x, uv.y, uv.z, uv.w};
    float w[4] = {wv.x, wv.y, wv.z, wv.w};
    float lb[4] = {bv.x, bv.y, bv.z, bv.w};
    float4 outv;
    float* op = (float*)&outv;
#pragma unroll
    for (int j = 0; j < 4; ++j)
        op[j] = ((o[j] - mu) * rs * w[j] + lb[j]) * u[j];
    *(float4*)&g[(size_t)row * D_ + c0] = outv;
}

// ---------------------------------------------------------------------------
extern "C" void kernel_launch(void* const* d_in, const int* in_sizes, int n_in,
                              void* d_out, int out_size, void* d_ws, size_t ws_size,
                              hipStream_t stream)
{
    const float* x     = (const float*)d_in[0];
    // d_in[1] (context) is unused by the reference
    const float* Wqkvu = (const float*)d_in[2];
    const float* bqkvu = (const float*)d_in[3];
    const float* Wout  = (const float*)d_in[4];
    const float* bout  = (const float*)d_in[5];
    const float* theta = (const float*)d_in[6];
    const float* ln_w  = (const float*)d_in[7];
    const float* ln_b  = (const float*)d_in[8];
    float* out = (float*)d_out;

    float* qkvu  = (float*)d_ws;                              // 4096*4096 f32 = 64 MiB
    float* kvbuf = qkvu + (size_t)ROWS * FOURD;               // 2*16*128*64 f32 = 1 MiB
    float* g     = kvbuf + (size_t)B_ * H_ * 128 * 64;        // 4096*1024 f32 = 16 MiB

    hipMemsetAsync(kvbuf, 0, (size_t)B_ * H_ * 128 * 64 * sizeof(float), stream);

    dim3 blk(256);
    // qkvu = x @ Wqkvu^T + b, silu on q,k columns (< 2048)
    gemm_nt<<<dim3(FOURD / 128, ROWS / 128), blk, 0, stream>>>(
        x, Wqkvu, bqkvu, qkvu, ROWS, FOURD, D_, 2 * D_);
    // KV = lrpe(k)^T v per (b,h)
    kv_kernel<<<dim3(B_ * H_ * 8), blk, 0, stream>>>(qkvu, theta, kvbuf);
    // o = lrpe(q) @ KV, fused LN + u gating
    attn_ln_kernel<<<dim3(ROWS), blk, 0, stream>>>(qkvu, kvbuf, theta, ln_w, ln_b, g);
    // out = g @ Wout^T + bout
    gemm_nt<<<dim3(D_ / 128, ROWS / 128), blk, 0, stream>>>(
        g, Wout, bout, out, ROWS, D_, D_, 0);
}

// Round 2
// 356.817 us; speedup vs baseline: 2.4339x; 2.4339x over previous
//
#include <hip/hip_runtime.h>
#include <math.h>

#define B_ 2
#define N_ 2048
#define D_ 1024
#define H_ 16
#define DH_ 64
#define ROWS (B_*N_)      // 4096
#define FOURD (4*D_)      // 4096
#define EPS_ 1e-5f

typedef short bf16x8 __attribute__((ext_vector_type(8)));
typedef float f32x4  __attribute__((ext_vector_type(4)));

__device__ __forceinline__ unsigned short f2bf(float f) {
    unsigned int x = __float_as_uint(f);
    unsigned int r = (x + 0x7fffu + ((x >> 16) & 1u)) >> 16;   // RNE
    return (unsigned short)r;
}

// ---------------------------------------------------------------------------
// fp32 -> bf16 cast, 4 elements/thread
// ---------------------------------------------------------------------------
__global__ __launch_bounds__(256)
void cast_f32_bf16(const float* __restrict__ in, unsigned short* __restrict__ out, int n4)
{
    int i = blockIdx.x * 256 + threadIdx.x;
    if (i >= n4) return;
    float4 v = ((const float4*)in)[i];
    ushort4 o;
    o.x = f2bf(v.x); o.y = f2bf(v.y); o.z = f2bf(v.z); o.w = f2bf(v.w);
    ((ushort4*)out)[i] = o;
}

// ---------------------------------------------------------------------------
// bf16 MFMA GEMM (m97 structure): C[M,N] = A[M,K] * Bw[N,K]^T + bias (fp32 out)
// A, Bw bf16 row-major (K contiguous). 128x128 tile, BK=32, 256 thr = 4 waves
// (2x2), each wave 64x64 via 4x4 tiles of v_mfma_f32_16x16x32_bf16.
// Optional silu on columns < siluLim. M,N,K multiples of 128/128/32.
// ---------------------------------------------------------------------------
__global__ __launch_bounds__(256)
void gemm_bt_mfma(const unsigned short* __restrict__ A,
                  const unsigned short* __restrict__ Bw,
                  const float* __restrict__ bias, float* __restrict__ C,
                  int M, int N, int K, int siluLim)
{
    __shared__ unsigned short As[128 * 32];   // row-major, 32 k per row
    __shared__ unsigned short Bs[128 * 32];

    const int tid  = threadIdx.x;
    const int row0 = blockIdx.y * 128;
    const int col0 = blockIdx.x * 128;
    const int wave = tid >> 6;
    const int lane = tid & 63;
    const int wr   = (wave >> 1) * 64;   // wave row offset in tile
    const int wc   = (wave & 1) * 64;    // wave col offset in tile
    const int l15  = lane & 15;
    const int quad = lane >> 4;

    f32x4 acc[4][4] = {};

    // staging: chunk c (0..511): row=c>>2, k-offset=(c&3)*8 bf16.
    // thread tid stages chunks tid and tid+256. LDS dest = base + tid*16B,
    // which within each wave is wave-uniform base + lane*16 (required).
    const int srow = tid >> 2;
    const int skk  = (tid & 3) * 8;
    const unsigned short* ag = A  + (size_t)(row0 + srow) * K + skk;
    const unsigned short* bg = Bw + (size_t)(col0 + srow) * K + skk;

    typedef const __attribute__((address_space(1))) unsigned int* gp_t;
    typedef __attribute__((address_space(3))) unsigned int* lp_t;
    lp_t asd = (lp_t)(void*)&As[tid * 8];
    lp_t bsd = (lp_t)(void*)&Bs[tid * 8];

    for (int k0 = 0; k0 < K; k0 += 32) {
        __builtin_amdgcn_global_load_lds((gp_t)(const void*)(ag + k0),            asd,        16, 0, 0);
        __builtin_amdgcn_global_load_lds((gp_t)(const void*)(ag + (size_t)64*K + k0), asd + 1024, 16, 0, 0);
        __builtin_amdgcn_global_load_lds((gp_t)(const void*)(bg + k0),            bsd,        16, 0, 0);
        __builtin_amdgcn_global_load_lds((gp_t)(const void*)(bg + (size_t)64*K + k0), bsd + 1024, 16, 0, 0);
        __syncthreads();   // drains vmcnt before barrier

        bf16x8 af[4], bfr[4];
#pragma unroll
        for (int i = 0; i < 4; ++i)
            af[i] = *(const bf16x8*)&As[(wr + i * 16 + l15) * 32 + quad * 8];
#pragma unroll
        for (int j = 0; j < 4; ++j)
            bfr[j] = *(const bf16x8*)&Bs[(wc + j * 16 + l15) * 32 + quad * 8];
#pragma unroll
        for (int i = 0; i < 4; ++i)
#pragma unroll
            for (int j = 0; j < 4; ++j)
                acc[i][j] = __builtin_amdgcn_mfma_f32_16x16x32_bf16(af[i], bfr[j], acc[i][j], 0, 0, 0);
        __syncthreads();
    }

    // epilogue: C/D layout col=lane&15, row=quad*4+reg
#pragma unroll
    for (int i = 0; i < 4; ++i) {
        const int r0 = row0 + wr + i * 16 + quad * 4;
#pragma unroll
        for (int j = 0; j < 4; ++j) {
            const int c = col0 + wc + j * 16 + l15;
            const float bb = bias[c];
#pragma unroll
            for (int r = 0; r < 4; ++r) {
                float v = acc[i][j][r] + bb;
                if (c < siluLim) v = v / (1.f + expf(-v));   // silu
                C[(size_t)(r0 + r) * N + c] = v;
            }
        }
    }
}

// ---------------------------------------------------------------------------
// KV[b,h,d,e] = sum_n lrpe(k)[n,d] * v[n,e];  d in [0,128), e in [0,64).
// One block per (b,h,chunk of 256 n), fp32 atomic accumulation.
// ---------------------------------------------------------------------------
__global__ __launch_bounds__(256)
void kv_kernel(const float* __restrict__ qkvu, const float* __restrict__ theta,
               float* __restrict__ kv)
{
    __shared__ float kl_s[64][128];
    __shared__ float v_s[64][64];

    const int bid   = blockIdx.x;
    const int chunk = bid & 7;
    const int h     = (bid >> 3) & 15;
    const int b     = bid >> 7;
    const int tid   = threadIdx.x;
    const int tr    = tid >> 4;
    const int tc    = tid & 15;

    float acc[8][4];
#pragma unroll
    for (int i = 0; i < 8; ++i)
#pragma unroll
        for (int j = 0; j < 4; ++j) acc[i][j] = 0.f;

    const int n0 = chunk * 256;
    for (int sub = 0; sub < 4; ++sub) {
        const int nbase = n0 + sub * 64;
        for (int idx = tid; idx < 64 * 128; idx += 256) {
            const int nn = idx >> 7, d = idx & 127, dh = d & 63;
            const int n = nbase + nn;
            const float kval = qkvu[(size_t)(b * N_ + n) * FOURD + D_ + h * DH_ + dh];
            const float th = theta[h * DH_ + dh] * (float)n;
            float s, c; sincosf(th, &s, &c);
            kl_s[nn][d] = kval * ((d < 64) ? c : s);
        }
        for (int idx = tid; idx < 64 * 64; idx += 256) {
            const int nn = idx >> 6, e = idx & 63;
            const int n = nbase + nn;
            v_s[nn][e] = qkvu[(size_t)(b * N_ + n) * FOURD + 2 * D_ + h * DH_ + e];
        }
        __syncthreads();

        for (int nn = 0; nn < 64; ++nn) {
            float4 x0 = *(const float4*)&kl_s[nn][tr*8];
            float4 x1 = *(const float4*)&kl_s[nn][tr*8 + 4];
            float4 y  = *(const float4*)&v_s[nn][tc*4];
            float a[8] = {x0.x, x0.y, x0.z, x0.w, x1.x, x1.y, x1.z, x1.w};
            float vv[4] = {y.x, y.y, y.z, y.w};
#pragma unroll
            for (int i = 0; i < 8; ++i)
#pragma unroll
                for (int j = 0; j < 4; ++j)
                    acc[i][j] = fmaf(a[i], vv[j], acc[i][j]);
        }
        __syncthreads();
    }

    float* kvb = kv + (size_t)(b * H_ + h) * 128 * 64;
#pragma unroll
    for (int i = 0; i < 8; ++i)
#pragma unroll
        for (int j = 0; j < 4; ++j)
            atomicAdd(&kvb[(tr * 8 + i) * 64 + tc * 4 + j], acc[i][j]);
}

// ---------------------------------------------------------------------------
// o = lrpe(q) @ KV, fused LayerNorm + u gating; writes g in bf16 for gemm2.
// One block (256 thr) per row, 4 cols/thread.
// ---------------------------------------------------------------------------
__global__ __launch_bounds__(256)
void attn_ln_kernel(const float* __restrict__ qkvu, const float* __restrict__ kv,
                    const float* __restrict__ theta, const float* __restrict__ ln_w,
                    const float* __restrict__ ln_b, unsigned short* __restrict__ g)
{
    __shared__ float qc_s[1024];
    __shared__ float qs_s[1024];
    __shared__ float red[16];

    const int row = blockIdx.x;
    const int b   = row >> 11;
    const int n   = row & (N_ - 1);
    const int tid = threadIdx.x;
    const int c0  = tid * 4;

    {
        float4 qv = *(const float4*)&qkvu[(size_t)row * FOURD + c0];
        float q[4] = {qv.x, qv.y, qv.z, qv.w};
#pragma unroll
        for (int j = 0; j < 4; ++j) {
            const int c = c0 + j;
            const float th = theta[c] * (float)n;
            float s, cc; sincosf(th, &s, &cc);
            qc_s[c] = q[j] * cc;
            qs_s[c] = q[j] * s;
        }
    }
    __syncthreads();

    const int h  = c0 >> 6;
    const int e0 = c0 & 63;
    const float* kvb = kv + (size_t)(b * H_ + h) * 8192;
    float o[4] = {0.f, 0.f, 0.f, 0.f};
    for (int d = 0; d < 64; ++d) {
        const float qc = qc_s[h * 64 + d];
        const float qs = qs_s[h * 64 + d];
        float4 kc = *(const float4*)&kvb[d * 64 + e0];
        float4 ks = *(const float4*)&kvb[(64 + d) * 64 + e0];
        o[0] = fmaf(qc, kc.x, fmaf(qs, ks.x, o[0]));
        o[1] = fmaf(qc, kc.y, fmaf(qs, ks.y, o[1]));
        o[2] = fmaf(qc, kc.z, fmaf(qs, ks.z, o[2]));
        o[3] = fmaf(qc, kc.w, fmaf(qs, ks.w, o[3]));
    }

    float sum = o[0] + o[1] + o[2] + o[3];
    float sq  = o[0]*o[0] + o[1]*o[1] + o[2]*o[2] + o[3]*o[3];
#pragma unroll
    for (int off = 32; off; off >>= 1) {
        sum += __shfl_down(sum, off, 64);
        sq  += __shfl_down(sq,  off, 64);
    }
    const int wave = tid >> 6;
    if ((tid & 63) == 0) { red[wave] = sum; red[4 + wave] = sq; }
    __syncthreads();
    if (tid == 0) {
        const float s  = red[0] + red[1] + red[2] + red[3];
        const float q2 = red[4] + red[5] + red[6] + red[7];
        const float mu = s * (1.f / (float)D_);
        const float var = q2 * (1.f / (float)D_) - mu * mu;
        red[8] = mu;
        red[9] = rsqrtf(var + EPS_);
    }
    __syncthreads();
    const float mu = red[8], rs = red[9];

    float4 uv = *(const float4*)&qkvu[(size_t)row * FOURD + 3 * D_ + c0];
    float4 wv = *(const float4*)&ln_w[c0];
    float4 bv = *(const float4*)&ln_b[c0];
    float u[4] = {uv.x, uv.y, uv.z, uv.w};
    float w[4] = {wv.x, wv.y, wv.z, wv.w};
    float lb[4] = {bv.x, bv.y, bv.z, bv.w};
    ushort4 ov;
    ov.x = f2bf(((o[0] - mu) * rs * w[0] + lb[0]) * u[0]);
    ov.y = f2bf(((o[1] - mu) * rs * w[1] + lb[1]) * u[1]);
    ov.z = f2bf(((o[2] - mu) * rs * w[2] + lb[2]) * u[2]);
    ov.w = f2bf(((o[3] - mu) * rs * w[3] + lb[3]) * u[3]);
    *(ushort4*)&g[(size_t)row * D_ + c0] = ov;
}

// ---------------------------------------------------------------------------
extern "C" void kernel_launch(void* const* d_in, const int* in_sizes, int n_in,
                              void* d_out, int out_size, void* d_ws, size_t ws_size,
                              hipStream_t stream)
{
    const float* x     = (const float*)d_in[0];
    const float* Wqkvu = (const float*)d_in[2];
    const float* bqkvu = (const float*)d_in[3];
    const float* Wout  = (const float*)d_in[4];
    const float* bout  = (const float*)d_in[5];
    const float* theta = (const float*)d_in[6];
    const float* ln_w  = (const float*)d_in[7];
    const float* ln_b  = (const float*)d_in[8];
    float* out = (float*)d_out;

    // workspace layout (bytes)
    char* ws = (char*)d_ws;
    float*          qkvu  = (float*)ws;                           ws += (size_t)ROWS * FOURD * 4;   // 64 MiB
    float*          kvbuf = (float*)ws;                           ws += (size_t)B_ * H_ * 128 * 64 * 4; // 1 MiB
    unsigned short* xb    = (unsigned short*)ws;                  ws += (size_t)ROWS * D_ * 2;      // 8 MiB
    unsigned short* wqb   = (unsigned short*)ws;                  ws += (size_t)FOURD * D_ * 2;     // 8 MiB
    unsigned short* wob   = (unsigned short*)ws;                  ws += (size_t)D_ * D_ * 2;        // 2 MiB
    unsigned short* gb    = (unsigned short*)ws;                  ws += (size_t)ROWS * D_ * 2;      // 8 MiB

    hipMemsetAsync(kvbuf, 0, (size_t)B_ * H_ * 128 * 64 * sizeof(float), stream);

    dim3 blk(256);
    // casts to bf16
    cast_f32_bf16<<<dim3(ROWS * D_ / 4 / 256), blk, 0, stream>>>(x, xb, ROWS * D_ / 4);
    cast_f32_bf16<<<dim3(FOURD * D_ / 4 / 256), blk, 0, stream>>>(Wqkvu, wqb, FOURD * D_ / 4);
    cast_f32_bf16<<<dim3(D_ * D_ / 4 / 256), blk, 0, stream>>>(Wout, wob, D_ * D_ / 4);

    // qkvu = x @ Wqkvu^T + b (fp32 out), silu on q,k columns (< 2048)
    gemm_bt_mfma<<<dim3(FOURD / 128, ROWS / 128), blk, 0, stream>>>(
        xb, wqb, bqkvu, qkvu, ROWS, FOURD, D_, 2 * D_);
    // KV = lrpe(k)^T v per (b,h)
    kv_kernel<<<dim3(B_ * H_ * 8), blk, 0, stream>>>(qkvu, theta, kvbuf);
    // o = lrpe(q) @ KV, fused LN + u gating -> g (bf16)
    attn_ln_kernel<<<dim3(ROWS), blk, 0, stream>>>(qkvu, kvbuf, theta, ln_w, ln_b, gb);
    // out = g @ Wout^T + bout
    gemm_bt_mfma<<<dim3(D_ / 128, ROWS / 128), blk, 0, stream>>>(
        gb, wob, bout, out, ROWS, D_, D_, 0);
}

// Round 3
// 242.358 us; speedup vs baseline: 3.5833x; 1.4723x over previous
//
#include <hip/hip_runtime.h>
#include <math.h>

#define B_ 2
#define N_ 2048
#define D_ 1024
#define H_ 16
#define DH_ 64
#define ROWS (B_*N_)      // 4096
#define FOURD (4*D_)      // 4096
#define EPS_ 1e-5f

typedef short bf16x8 __attribute__((ext_vector_type(8)));
typedef float f32x4  __attribute__((ext_vector_type(4)));

__device__ __forceinline__ unsigned short f2bf(float f) {
    unsigned int x = __float_as_uint(f);
    unsigned int r = (x + 0x7fffu + ((x >> 16) & 1u)) >> 16;   // RNE
    return (unsigned short)r;
}

// ---------------------------------------------------------------------------
// fp32 -> bf16 cast, 4 elements/thread
// ---------------------------------------------------------------------------
__global__ __launch_bounds__(256)
void cast_f32_bf16(const float* __restrict__ in, unsigned short* __restrict__ out, int n4)
{
    int i = blockIdx.x * 256 + threadIdx.x;
    if (i >= n4) return;
    float4 v = ((const float4*)in)[i];
    ushort4 o;
    o.x = f2bf(v.x); o.y = f2bf(v.y); o.z = f2bf(v.z); o.w = f2bf(v.w);
    ((ushort4*)out)[i] = o;
}

// ---------------------------------------------------------------------------
// bf16 MFMA GEMM (m97 structure): C[M,N] = A[M,K] * Bw[N,K]^T + bias (fp32 out)
// 128x128 tile, BK=32, 4 waves (2x2), 4x4 tiles of v_mfma_f32_16x16x32_bf16.
// ---------------------------------------------------------------------------
__global__ __launch_bounds__(256)
void gemm_bt_mfma(const unsigned short* __restrict__ A,
                  const unsigned short* __restrict__ Bw,
                  const float* __restrict__ bias, float* __restrict__ C,
                  int M, int N, int K, int siluLim)
{
    __shared__ unsigned short As[128 * 32];
    __shared__ unsigned short Bs[128 * 32];

    const int tid  = threadIdx.x;
    const int row0 = blockIdx.y * 128;
    const int col0 = blockIdx.x * 128;
    const int wave = tid >> 6;
    const int lane = tid & 63;
    const int wr   = (wave >> 1) * 64;
    const int wc   = (wave & 1) * 64;
    const int l15  = lane & 15;
    const int quad = lane >> 4;

    f32x4 acc[4][4] = {};

    const int srow = tid >> 2;
    const int skk  = (tid & 3) * 8;
    const unsigned short* ag = A  + (size_t)(row0 + srow) * K + skk;
    const unsigned short* bg = Bw + (size_t)(col0 + srow) * K + skk;

    typedef const __attribute__((address_space(1))) unsigned int* gp_t;
    typedef __attribute__((address_space(3))) unsigned int* lp_t;
    lp_t asd = (lp_t)(void*)&As[tid * 8];
    lp_t bsd = (lp_t)(void*)&Bs[tid * 8];

    for (int k0 = 0; k0 < K; k0 += 32) {
        __builtin_amdgcn_global_load_lds((gp_t)(const void*)(ag + k0),                asd,        16, 0, 0);
        __builtin_amdgcn_global_load_lds((gp_t)(const void*)(ag + (size_t)64*K + k0), asd + 1024, 16, 0, 0);
        __builtin_amdgcn_global_load_lds((gp_t)(const void*)(bg + k0),                bsd,        16, 0, 0);
        __builtin_amdgcn_global_load_lds((gp_t)(const void*)(bg + (size_t)64*K + k0), bsd + 1024, 16, 0, 0);
        __syncthreads();

        bf16x8 af[4], bfr[4];
#pragma unroll
        for (int i = 0; i < 4; ++i)
            af[i] = *(const bf16x8*)&As[(wr + i * 16 + l15) * 32 + quad * 8];
#pragma unroll
        for (int j = 0; j < 4; ++j)
            bfr[j] = *(const bf16x8*)&Bs[(wc + j * 16 + l15) * 32 + quad * 8];
#pragma unroll
        for (int i = 0; i < 4; ++i)
#pragma unroll
            for (int j = 0; j < 4; ++j)
                acc[i][j] = __builtin_amdgcn_mfma_f32_16x16x32_bf16(af[i], bfr[j], acc[i][j], 0, 0, 0);
        __syncthreads();
    }

#pragma unroll
    for (int i = 0; i < 4; ++i) {
        const int r0 = row0 + wr + i * 16 + quad * 4;
#pragma unroll
        for (int j = 0; j < 4; ++j) {
            const int c = col0 + wc + j * 16 + l15;
            const float bb = bias[c];
#pragma unroll
            for (int r = 0; r < 4; ++r) {
                float v = acc[i][j][r] + bb;
                if (c < siluLim) v = v / (1.f + expf(-v));   // silu
                C[(size_t)(r0 + r) * N + c] = v;
            }
        }
    }
}

// ---------------------------------------------------------------------------
// kv_mfma: per (b,h): partial KV[128 d, 64 e] over a 128-n chunk via MFMA.
// A[d][n] = lrpe(k)[n,d] (bf16, staged transposed), B[n][e] = v (staged as
// [e][n] so B-fragments are contiguous). No atomics: fp32 partials to ws.
// grid = 32 bh * 16 chunks, 256 threads (4 waves; wave w owns d in [32w,32w+32)).
// ---------------------------------------------------------------------------
__global__ __launch_bounds__(256)
void kv_mfma(const float* __restrict__ qkvu, const float* __restrict__ theta,
             float* __restrict__ part)
{
    __shared__ unsigned short kl_s[128][136];  // [d][n], pad 8 -> <=2-way conflicts
    __shared__ unsigned short v_s [64][136];   // [e][n]

    const int bid   = blockIdx.x;
    const int chunk = bid & 15;
    const int bh    = bid >> 4;
    const int h     = bh & 15;
    const int b     = bh >> 4;
    const int tid   = threadIdx.x;
    const int lane  = tid & 63;
    const int wave  = tid >> 6;
    const int l15   = lane & 15;
    const int quad  = lane >> 4;
    const int n0    = chunk * 128;

    // stage: i -> nn = i>>4 (0..127), dh0 = (i&15)*4
    for (int i = tid; i < 2048; i += 256) {
        const int nn  = i >> 4;
        const int dh0 = (i & 15) * 4;
        const int n   = n0 + nn;
        const float* qrow = qkvu + (size_t)(b * N_ + n) * FOURD;
        float4 k4 = *(const float4*)(qrow + D_     + h * DH_ + dh0);
        float4 v4 = *(const float4*)(qrow + 2 * D_ + h * DH_ + dh0);
        float kk[4] = {k4.x, k4.y, k4.z, k4.w};
        float vv[4] = {v4.x, v4.y, v4.z, v4.w};
#pragma unroll
        for (int j = 0; j < 4; ++j) {
            const int dh = dh0 + j;
            float s, c; sincosf(theta[h * DH_ + dh] * (float)n, &s, &c);
            kl_s[dh][nn]      = f2bf(kk[j] * c);
            kl_s[64 + dh][nn] = f2bf(kk[j] * s);
            v_s[dh][nn]       = f2bf(vv[j]);    // dh doubles as e index
        }
    }
    __syncthreads();

    f32x4 acc[2][4] = {};
#pragma unroll
    for (int ks = 0; ks < 4; ++ks) {            // K = 128 in steps of 32
        bf16x8 a0 = *(const bf16x8*)&kl_s[wave * 32 +      l15][ks * 32 + quad * 8];
        bf16x8 a1 = *(const bf16x8*)&kl_s[wave * 32 + 16 + l15][ks * 32 + quad * 8];
#pragma unroll
        for (int j = 0; j < 4; ++j) {
            bf16x8 bfr = *(const bf16x8*)&v_s[j * 16 + l15][ks * 32 + quad * 8];
            acc[0][j] = __builtin_amdgcn_mfma_f32_16x16x32_bf16(a0, bfr, acc[0][j], 0, 0, 0);
            acc[1][j] = __builtin_amdgcn_mfma_f32_16x16x32_bf16(a1, bfr, acc[1][j], 0, 0, 0);
        }
    }

    float* pp = part + ((size_t)bh * 16 + chunk) * 8192;
#pragma unroll
    for (int i = 0; i < 2; ++i) {
        const int d0 = wave * 32 + i * 16 + quad * 4;
#pragma unroll
        for (int j = 0; j < 4; ++j) {
            const int e = j * 16 + l15;
#pragma unroll
            for (int r = 0; r < 4; ++r)
                pp[(d0 + r) * 64 + e] = acc[i][j][r];
        }
    }
}

// ---------------------------------------------------------------------------
// kv_reduce: kv[bh][i] = sum over 16 chunk partials. 32*8192 outputs.
// ---------------------------------------------------------------------------
__global__ __launch_bounds__(256)
void kv_reduce(const float* __restrict__ part, float* __restrict__ kv)
{
    const int i  = blockIdx.x * 256 + threadIdx.x;
    const int bh = i >> 13;
    const float* pp = part + ((size_t)bh * 16) * 8192 + (i & 8191);
    float s = 0.f;
#pragma unroll
    for (int c = 0; c < 16; ++c) s += pp[c * 8192];
    kv[i] = s;
}

// ---------------------------------------------------------------------------
// attn_ln: 8 rows per block. o = lrpe(q) @ KV (fp32), fused LayerNorm +
// u gating, bf16 output. KV[b] (512 KB) read once per 8 rows.
// ---------------------------------------------------------------------------
__global__ __launch_bounds__(256)
void attn_ln_kernel(const float* __restrict__ qkvu, const float* __restrict__ kvb,
                    const float* __restrict__ theta, const float* __restrict__ ln_w,
                    const float* __restrict__ ln_b, unsigned short* __restrict__ g)
{
    __shared__ float qc_s[8][1024];
    __shared__ float qs_s[8][1024];
    __shared__ float red[4][16];
    __shared__ float mured[8], rsred[8];

    const int row0 = blockIdx.x * 8;
    const int b    = row0 >> 11;
    const int tid  = threadIdx.x;
    const int lane = tid & 63;
    const int wave = tid >> 6;

    // stage q*cos / q*sin for 8 rows
    for (int i = tid; i < 2048; i += 256) {
        const int r  = i >> 8;
        const int c0 = (i & 255) * 4;
        const int n  = (row0 + r) & (N_ - 1);
        float4 qv = *(const float4*)&qkvu[(size_t)(row0 + r) * FOURD + c0];
        float4 tv = *(const float4*)&theta[c0];
        float q[4] = {qv.x, qv.y, qv.z, qv.w};
        float t[4] = {tv.x, tv.y, tv.z, tv.w};
        float4 cv, sv;
        float* cp = (float*)&cv; float* sp = (float*)&sv;
#pragma unroll
        for (int j = 0; j < 4; ++j) {
            float s, c; sincosf(t[j] * (float)n, &s, &c);
            cp[j] = q[j] * c; sp[j] = q[j] * s;
        }
        *(float4*)&qc_s[r][c0] = cv;
        *(float4*)&qs_s[r][c0] = sv;
    }
    __syncthreads();

    const int c0 = tid * 4;           // [0,1024)
    const int h  = c0 >> 6;
    const int e0 = c0 & 63;
    const float* kvp = kvb + (size_t)(b * H_ + h) * 8192;

    float o[8][4] = {};
    for (int d = 0; d < 64; ++d) {
        float4 kc = *(const float4*)&kvp[d * 64 + e0];
        float4 ks = *(const float4*)&kvp[(64 + d) * 64 + e0];
#pragma unroll
        for (int r = 0; r < 8; ++r) {
            const float qc = qc_s[r][h * 64 + d];
            const float qs = qs_s[r][h * 64 + d];
            o[r][0] = fmaf(qc, kc.x, fmaf(qs, ks.x, o[r][0]));
            o[r][1] = fmaf(qc, kc.y, fmaf(qs, ks.y, o[r][1]));
            o[r][2] = fmaf(qc, kc.z, fmaf(qs, ks.z, o[r][2]));
            o[r][3] = fmaf(qc, kc.w, fmaf(qs, ks.w, o[r][3]));
        }
    }

    // per-row LN stats across all 256 threads
    float sum[8], sq[8];
#pragma unroll
    for (int r = 0; r < 8; ++r) {
        sum[r] = o[r][0] + o[r][1] + o[r][2] + o[r][3];
        sq[r]  = o[r][0]*o[r][0] + o[r][1]*o[r][1] + o[r][2]*o[r][2] + o[r][3]*o[r][3];
    }
#pragma unroll
    for (int off = 32; off; off >>= 1)
#pragma unroll
        for (int r = 0; r < 8; ++r) {
            sum[r] += __shfl_down(sum[r], off, 64);
            sq[r]  += __shfl_down(sq[r],  off, 64);
        }
    if (lane == 0)
#pragma unroll
        for (int r = 0; r < 8; ++r) { red[wave][r] = sum[r]; red[wave][8 + r] = sq[r]; }
    __syncthreads();
    if (tid < 8) {
        const float s  = red[0][tid] + red[1][tid] + red[2][tid] + red[3][tid];
        const float q2 = red[0][8+tid] + red[1][8+tid] + red[2][8+tid] + red[3][8+tid];
        const float mu = s * (1.f / (float)D_);
        const float var = q2 * (1.f / (float)D_) - mu * mu;
        mured[tid] = mu;
        rsred[tid] = rsqrtf(var + EPS_);
    }
    __syncthreads();

    float4 wv = *(const float4*)&ln_w[c0];
    float4 bv = *(const float4*)&ln_b[c0];
#pragma unroll
    for (int r = 0; r < 8; ++r) {
        float4 uv = *(const float4*)&qkvu[(size_t)(row0 + r) * FOURD + 3 * D_ + c0];
        const float mu = mured[r], rs = rsred[r];
        ushort4 ov;
        ov.x = f2bf(((o[r][0] - mu) * rs * wv.x + bv.x) * uv.x);
        ov.y = f2bf(((o[r][1] - mu) * rs * wv.y + bv.y) * uv.y);
        ov.z = f2bf(((o[r][2] - mu) * rs * wv.z + bv.z) * uv.z);
        ov.w = f2bf(((o[r][3] - mu) * rs * wv.w + bv.w) * uv.w);
        *(ushort4*)&g[(size_t)(row0 + r) * D_ + c0] = ov;
    }
}

// ---------------------------------------------------------------------------
extern "C" void kernel_launch(void* const* d_in, const int* in_sizes, int n_in,
                              void* d_out, int out_size, void* d_ws, size_t ws_size,
                              hipStream_t stream)
{
    const float* x     = (const float*)d_in[0];
    const float* Wqkvu = (const float*)d_in[2];
    const float* bqkvu = (const float*)d_in[3];
    const float* Wout  = (const float*)d_in[4];
    const float* bout  = (const float*)d_in[5];
    const float* theta = (const float*)d_in[6];
    const float* ln_w  = (const float*)d_in[7];
    const float* ln_b  = (const float*)d_in[8];
    float* out = (float*)d_out;

    // workspace layout
    char* ws = (char*)d_ws;
    float*          qkvu  = (float*)ws;          ws += (size_t)ROWS * FOURD * 4;          // 64 MiB
    float*          kvbuf = (float*)ws;          ws += (size_t)B_ * H_ * 8192 * 4;        // 1 MiB
    unsigned short* wqb   = (unsigned short*)ws; ws += (size_t)FOURD * D_ * 2;            // 8 MiB
    unsigned short* wob   = (unsigned short*)ws; ws += (size_t)D_ * D_ * 2;               // 2 MiB
    unsigned short* xb    = (unsigned short*)ws; ws += (size_t)ROWS * D_ * 2;             // 8 MiB
    // big scratch: kv partials (16 MiB) early, then g (bf16, 8 MiB) aliases it
    float*          part  = (float*)ws;
    unsigned short* gb    = (unsigned short*)ws; // alias: part dead before attn writes g

    dim3 blk(256);
    cast_f32_bf16<<<dim3(ROWS * D_ / 4 / 256), blk, 0, stream>>>(x, xb, ROWS * D_ / 4);
    cast_f32_bf16<<<dim3(FOURD * D_ / 4 / 256), blk, 0, stream>>>(Wqkvu, wqb, FOURD * D_ / 4);
    cast_f32_bf16<<<dim3(D_ * D_ / 4 / 256), blk, 0, stream>>>(Wout, wob, D_ * D_ / 4);

    // qkvu = x @ Wqkvu^T + b (fp32 out), silu on q,k columns
    gemm_bt_mfma<<<dim3(FOURD / 128, ROWS / 128), blk, 0, stream>>>(
        xb, wqb, bqkvu, qkvu, ROWS, FOURD, D_, 2 * D_);
    // KV partials + reduce
    kv_mfma<<<dim3(32 * 16), blk, 0, stream>>>(qkvu, theta, part);
    kv_reduce<<<dim3(32 * 8192 / 256), blk, 0, stream>>>(part, kvbuf);
    // o = lrpe(q) @ KV, fused LN + u gating -> g (bf16)
    attn_ln_kernel<<<dim3(ROWS / 8), blk, 0, stream>>>(qkvu, kvbuf, theta, ln_w, ln_b, gb);
    // out = g @ Wout^T + bout
    gemm_bt_mfma<<<dim3(D_ / 128, ROWS / 128), blk, 0, stream>>>(
        gb, wob, bout, out, ROWS, D_, D_, 0);
}

// Round 4
// 232.624 us; speedup vs baseline: 3.7333x; 1.0418x over previous
//
#include <hip/hip_runtime.h>
#include <math.h>

#define B_ 2
#define N_ 2048
#define D_ 1024
#define H_ 16
#define DH_ 64
#define ROWS (B_*N_)      // 4096
#define FOURD (4*D_)      // 4096
#define EPS_ 1e-5f

typedef short bf16x8 __attribute__((ext_vector_type(8)));
typedef unsigned short u16x8 __attribute__((ext_vector_type(8)));
typedef float f32x4  __attribute__((ext_vector_type(4)));

__device__ __forceinline__ unsigned short f2bf(float f) {
    unsigned int x = __float_as_uint(f);
    unsigned int r = (x + 0x7fffu + ((x >> 16) & 1u)) >> 16;   // RNE
    return (unsigned short)r;
}
__device__ __forceinline__ float bf2f(unsigned short u) {
    return __uint_as_float((unsigned int)u << 16);
}

// ---------------------------------------------------------------------------
// fp32 -> bf16 cast, 4 elements/thread
// ---------------------------------------------------------------------------
__global__ __launch_bounds__(256)
void cast_f32_bf16(const float* __restrict__ in, unsigned short* __restrict__ out, int n4)
{
    int i = blockIdx.x * 256 + threadIdx.x;
    if (i >= n4) return;
    float4 v = ((const float4*)in)[i];
    ushort4 o;
    o.x = f2bf(v.x); o.y = f2bf(v.y); o.z = f2bf(v.z); o.w = f2bf(v.w);
    ((ushort4*)out)[i] = o;
}

// ---------------------------------------------------------------------------
// bf16 MFMA GEMM, 128x128 tile: C = A[M,K] * Bw[N,K]^T + bias, bf16 output,
// silu on columns < siluLim. Used for the big QKVU projection.
// ---------------------------------------------------------------------------
__global__ __launch_bounds__(256)
void gemm_bt_128(const unsigned short* __restrict__ A,
                 const unsigned short* __restrict__ Bw,
                 const float* __restrict__ bias, unsigned short* __restrict__ C,
                 int M, int N, int K, int siluLim)
{
    __shared__ unsigned short As[128 * 32];
    __shared__ unsigned short Bs[128 * 32];

    const int tid  = threadIdx.x;
    const int row0 = blockIdx.y * 128;
    const int col0 = blockIdx.x * 128;
    const int wave = tid >> 6;
    const int lane = tid & 63;
    const int wr   = (wave >> 1) * 64;
    const int wc   = (wave & 1) * 64;
    const int l15  = lane & 15;
    const int quad = lane >> 4;

    f32x4 acc[4][4] = {};

    const int srow = tid >> 2;
    const int skk  = (tid & 3) * 8;
    const unsigned short* ag = A  + (size_t)(row0 + srow) * K + skk;
    const unsigned short* bg = Bw + (size_t)(col0 + srow) * K + skk;

    typedef const __attribute__((address_space(1))) unsigned int* gp_t;
    typedef __attribute__((address_space(3))) unsigned int* lp_t;
    lp_t asd = (lp_t)(void*)&As[tid * 8];
    lp_t bsd = (lp_t)(void*)&Bs[tid * 8];

    for (int k0 = 0; k0 < K; k0 += 32) {
        __builtin_amdgcn_global_load_lds((gp_t)(const void*)(ag + k0),                asd,        16, 0, 0);
        __builtin_amdgcn_global_load_lds((gp_t)(const void*)(ag + (size_t)64*K + k0), asd + 1024, 16, 0, 0);
        __builtin_amdgcn_global_load_lds((gp_t)(const void*)(bg + k0),                bsd,        16, 0, 0);
        __builtin_amdgcn_global_load_lds((gp_t)(const void*)(bg + (size_t)64*K + k0), bsd + 1024, 16, 0, 0);
        __syncthreads();

        bf16x8 af[4], bfr[4];
#pragma unroll
        for (int i = 0; i < 4; ++i)
            af[i] = *(const bf16x8*)&As[(wr + i * 16 + l15) * 32 + quad * 8];
#pragma unroll
        for (int j = 0; j < 4; ++j)
            bfr[j] = *(const bf16x8*)&Bs[(wc + j * 16 + l15) * 32 + quad * 8];
#pragma unroll
        for (int i = 0; i < 4; ++i)
#pragma unroll
            for (int j = 0; j < 4; ++j)
                acc[i][j] = __builtin_amdgcn_mfma_f32_16x16x32_bf16(af[i], bfr[j], acc[i][j], 0, 0, 0);
        __syncthreads();
    }

#pragma unroll
    for (int i = 0; i < 4; ++i) {
        const int r0 = row0 + wr + i * 16 + quad * 4;
#pragma unroll
        for (int j = 0; j < 4; ++j) {
            const int c = col0 + wc + j * 16 + l15;
            const float bb = bias[c];
#pragma unroll
            for (int r = 0; r < 4; ++r) {
                float v = acc[i][j][r] + bb;
                if (c < siluLim) v = v / (1.f + expf(-v));   // silu
                C[(size_t)(r0 + r) * N + c] = f2bf(v);
            }
        }
    }
}

// ---------------------------------------------------------------------------
// bf16 MFMA GEMM, 128x64 tile (doubles block count for N=1024), fp32 output.
// 4 waves stacked in rows: wave w owns rows [32w,32w+32) x all 64 cols.
// ---------------------------------------------------------------------------
__global__ __launch_bounds__(256)
void gemm_bt_64(const unsigned short* __restrict__ A,
                const unsigned short* __restrict__ Bw,
                const float* __restrict__ bias, float* __restrict__ C,
                int M, int N, int K)
{
    __shared__ unsigned short As[128 * 32];
    __shared__ unsigned short Bs[64 * 32];

    const int tid  = threadIdx.x;
    const int row0 = blockIdx.y * 128;
    const int col0 = blockIdx.x * 64;
    const int wave = tid >> 6;
    const int lane = tid & 63;
    const int wr   = wave * 32;
    const int l15  = lane & 15;
    const int quad = lane >> 4;

    f32x4 acc[2][4] = {};

    const int srow = tid >> 2;
    const int skk  = (tid & 3) * 8;
    const unsigned short* ag = A  + (size_t)(row0 + srow) * K + skk;
    const unsigned short* bg = Bw + (size_t)(col0 + srow) * K + skk;

    typedef const __attribute__((address_space(1))) unsigned int* gp_t;
    typedef __attribute__((address_space(3))) unsigned int* lp_t;
    lp_t asd = (lp_t)(void*)&As[tid * 8];
    lp_t bsd = (lp_t)(void*)&Bs[tid * 8];

    for (int k0 = 0; k0 < K; k0 += 32) {
        __builtin_amdgcn_global_load_lds((gp_t)(const void*)(ag + k0),                asd,        16, 0, 0);
        __builtin_amdgcn_global_load_lds((gp_t)(const void*)(ag + (size_t)64*K + k0), asd + 1024, 16, 0, 0);
        __builtin_amdgcn_global_load_lds((gp_t)(const void*)(bg + k0),                bsd,        16, 0, 0);
        __syncthreads();

        bf16x8 af[2], bfr[4];
#pragma unroll
        for (int i = 0; i < 2; ++i)
            af[i] = *(const bf16x8*)&As[(wr + i * 16 + l15) * 32 + quad * 8];
#pragma unroll
        for (int j = 0; j < 4; ++j)
            bfr[j] = *(const bf16x8*)&Bs[(j * 16 + l15) * 32 + quad * 8];
#pragma unroll
        for (int i = 0; i < 2; ++i)
#pragma unroll
            for (int j = 0; j < 4; ++j)
                acc[i][j] = __builtin_amdgcn_mfma_f32_16x16x32_bf16(af[i], bfr[j], acc[i][j], 0, 0, 0);
        __syncthreads();
    }

#pragma unroll
    for (int i = 0; i < 2; ++i) {
        const int r0 = row0 + wr + i * 16 + quad * 4;
#pragma unroll
        for (int j = 0; j < 4; ++j) {
            const int c = col0 + j * 16 + l15;
            const float bb = bias[c];
#pragma unroll
            for (int r = 0; r < 4; ++r)
                C[(size_t)(r0 + r) * N + c] = acc[i][j][r] + bb;
        }
    }
}

// ---------------------------------------------------------------------------
// kv_mfma: per (b,h): partial KV[128 d, 64 e] over a 128-n chunk via MFMA.
// qkvu is bf16 now. grid = 32 bh * 16 chunks.
// ---------------------------------------------------------------------------
__global__ __launch_bounds__(256)
void kv_mfma(const unsigned short* __restrict__ qkvu, const float* __restrict__ theta,
             float* __restrict__ part)
{
    __shared__ unsigned short kl_s[128][136];  // [d][n], pad 8
    __shared__ unsigned short v_s [64][136];   // [e][n]

    const int bid   = blockIdx.x;
    const int chunk = bid & 15;
    const int bh    = bid >> 4;
    const int h     = bh & 15;
    const int b     = bh >> 4;
    const int tid   = threadIdx.x;
    const int lane  = tid & 63;
    const int wave  = tid >> 6;
    const int l15   = lane & 15;
    const int quad  = lane >> 4;
    const int n0    = chunk * 128;

    // stage: i -> nn = i>>3 (0..127), dh0 = (i&7)*8
    for (int i = tid; i < 1024; i += 256) {
        const int nn  = i >> 3;
        const int dh0 = (i & 7) * 8;
        const int n   = n0 + nn;
        const unsigned short* qrow = qkvu + (size_t)(b * N_ + n) * FOURD;
        u16x8 k8 = *(const u16x8*)(qrow + D_     + h * DH_ + dh0);
        u16x8 v8 = *(const u16x8*)(qrow + 2 * D_ + h * DH_ + dh0);
#pragma unroll
        for (int j = 0; j < 8; ++j) {
            const int dh = dh0 + j;
            const float kf = bf2f(k8[j]);
            float s, c; sincosf(theta[h * DH_ + dh] * (float)n, &s, &c);
            kl_s[dh][nn]      = f2bf(kf * c);
            kl_s[64 + dh][nn] = f2bf(kf * s);
            v_s[dh][nn]       = v8[j];          // dh doubles as e index
        }
    }
    __syncthreads();

    f32x4 acc[2][4] = {};
#pragma unroll
    for (int ks = 0; ks < 4; ++ks) {            // K = 128 in steps of 32
        bf16x8 a0 = *(const bf16x8*)&kl_s[wave * 32 +      l15][ks * 32 + quad * 8];
        bf16x8 a1 = *(const bf16x8*)&kl_s[wave * 32 + 16 + l15][ks * 32 + quad * 8];
#pragma unroll
        for (int j = 0; j < 4; ++j) {
            bf16x8 bfr = *(const bf16x8*)&v_s[j * 16 + l15][ks * 32 + quad * 8];
            acc[0][j] = __builtin_amdgcn_mfma_f32_16x16x32_bf16(a0, bfr, acc[0][j], 0, 0, 0);
            acc[1][j] = __builtin_amdgcn_mfma_f32_16x16x32_bf16(a1, bfr, acc[1][j], 0, 0, 0);
        }
    }

    float* pp = part + ((size_t)bh * 16 + chunk) * 8192;
#pragma unroll
    for (int i = 0; i < 2; ++i) {
        const int d0 = wave * 32 + i * 16 + quad * 4;
#pragma unroll
        for (int j = 0; j < 4; ++j) {
            const int e = j * 16 + l15;
#pragma unroll
            for (int r = 0; r < 4; ++r)
                pp[(d0 + r) * 64 + e] = acc[i][j][r];
        }
    }
}

// ---------------------------------------------------------------------------
// kv_reduce: kv[bh][i] = sum over 16 chunk partials.
// ---------------------------------------------------------------------------
__global__ __launch_bounds__(256)
void kv_reduce(const float* __restrict__ part, float* __restrict__ kv)
{
    const int i  = blockIdx.x * 256 + threadIdx.x;
    const int bh = i >> 13;
    const float* pp = part + ((size_t)bh * 16) * 8192 + (i & 8191);
    float s = 0.f;
#pragma unroll
    for (int c = 0; c < 16; ++c) s += pp[c * 8192];
    kv[i] = s;
}

// ---------------------------------------------------------------------------
// attn_ln: 8 rows per block. o = lrpe(q) @ KV (fp32), fused LayerNorm +
// u gating, bf16 output. qkvu is bf16 now.
// ---------------------------------------------------------------------------
__global__ __launch_bounds__(256)
void attn_ln_kernel(const unsigned short* __restrict__ qkvu, const float* __restrict__ kvb,
                    const float* __restrict__ theta, const float* __restrict__ ln_w,
                    const float* __restrict__ ln_b, unsigned short* __restrict__ g)
{
    __shared__ float qc_s[8][1024];
    __shared__ float qs_s[8][1024];
    __shared__ float red[4][16];
    __shared__ float mured[8], rsred[8];

    const int row0 = blockIdx.x * 8;
    const int b    = row0 >> 11;
    const int tid  = threadIdx.x;
    const int lane = tid & 63;
    const int wave = tid >> 6;

    // stage q*cos / q*sin for 8 rows
    for (int i = tid; i < 2048; i += 256) {
        const int r  = i >> 8;
        const int c0 = (i & 255) * 4;
        const int n  = (row0 + r) & (N_ - 1);
        ushort4 qv = *(const ushort4*)&qkvu[(size_t)(row0 + r) * FOURD + c0];
        float4 tv = *(const float4*)&theta[c0];
        float q[4] = {bf2f(qv.x), bf2f(qv.y), bf2f(qv.z), bf2f(qv.w)};
        float t[4] = {tv.x, tv.y, tv.z, tv.w};
        float4 cv, sv;
        float* cp = (float*)&cv; float* sp = (float*)&sv;
#pragma unroll
        for (int j = 0; j < 4; ++j) {
            float s, c; sincosf(t[j] * (float)n, &s, &c);
            cp[j] = q[j] * c; sp[j] = q[j] * s;
        }
        *(float4*)&qc_s[r][c0] = cv;
        *(float4*)&qs_s[r][c0] = sv;
    }
    __syncthreads();

    const int c0 = tid * 4;
    const int h  = c0 >> 6;
    const int e0 = c0 & 63;
    const float* kvp = kvb + (size_t)(b * H_ + h) * 8192;

    float o[8][4] = {};
    for (int d = 0; d < 64; ++d) {
        float4 kc = *(const float4*)&kvp[d * 64 + e0];
        float4 ks = *(const float4*)&kvp[(64 + d) * 64 + e0];
#pragma unroll
        for (int r = 0; r < 8; ++r) {
            const float qc = qc_s[r][h * 64 + d];
            const float qs = qs_s[r][h * 64 + d];
            o[r][0] = fmaf(qc, kc.x, fmaf(qs, ks.x, o[r][0]));
            o[r][1] = fmaf(qc, kc.y, fmaf(qs, ks.y, o[r][1]));
            o[r][2] = fmaf(qc, kc.z, fmaf(qs, ks.z, o[r][2]));
            o[r][3] = fmaf(qc, kc.w, fmaf(qs, ks.w, o[r][3]));
        }
    }

    float sum[8], sq[8];
#pragma unroll
    for (int r = 0; r < 8; ++r) {
        sum[r] = o[r][0] + o[r][1] + o[r][2] + o[r][3];
        sq[r]  = o[r][0]*o[r][0] + o[r][1]*o[r][1] + o[r][2]*o[r][2] + o[r][3]*o[r][3];
    }
#pragma unroll
    for (int off = 32; off; off >>= 1)
#pragma unroll
        for (int r = 0; r < 8; ++r) {
            sum[r] += __shfl_down(sum[r], off, 64);
            sq[r]  += __shfl_down(sq[r],  off, 64);
        }
    if (lane == 0)
#pragma unroll
        for (int r = 0; r < 8; ++r) { red[wave][r] = sum[r]; red[wave][8 + r] = sq[r]; }
    __syncthreads();
    if (tid < 8) {
        const float s  = red[0][tid] + red[1][tid] + red[2][tid] + red[3][tid];
        const float q2 = red[0][8+tid] + red[1][8+tid] + red[2][8+tid] + red[3][8+tid];
        const float mu = s * (1.f / (float)D_);
        const float var = q2 * (1.f / (float)D_) - mu * mu;
        mured[tid] = mu;
        rsred[tid] = rsqrtf(var + EPS_);
    }
    __syncthreads();

    float4 wv = *(const float4*)&ln_w[c0];
    float4 bv = *(const float4*)&ln_b[c0];
#pragma unroll
    for (int r = 0; r < 8; ++r) {
        ushort4 uvb = *(const ushort4*)&qkvu[(size_t)(row0 + r) * FOURD + 3 * D_ + c0];
        const float mu = mured[r], rs = rsred[r];
        ushort4 ov;
        ov.x = f2bf(((o[r][0] - mu) * rs * wv.x + bv.x) * bf2f(uvb.x));
        ov.y = f2bf(((o[r][1] - mu) * rs * wv.y + bv.y) * bf2f(uvb.y));
        ov.z = f2bf(((o[r][2] - mu) * rs * wv.z + bv.z) * bf2f(uvb.z));
        ov.w = f2bf(((o[r][3] - mu) * rs * wv.w + bv.w) * bf2f(uvb.w));
        *(ushort4*)&g[(size_t)(row0 + r) * D_ + c0] = ov;
    }
}

// ---------------------------------------------------------------------------
extern "C" void kernel_launch(void* const* d_in, const int* in_sizes, int n_in,
                              void* d_out, int out_size, void* d_ws, size_t ws_size,
                              hipStream_t stream)
{
    const float* x     = (const float*)d_in[0];
    const float* Wqkvu = (const float*)d_in[2];
    const float* bqkvu = (const float*)d_in[3];
    const float* Wout  = (const float*)d_in[4];
    const float* bout  = (const float*)d_in[5];
    const float* theta = (const float*)d_in[6];
    const float* ln_w  = (const float*)d_in[7];
    const float* ln_b  = (const float*)d_in[8];
    float* out = (float*)d_out;

    // workspace layout
    char* ws = (char*)d_ws;
    unsigned short* qkvu  = (unsigned short*)ws; ws += (size_t)ROWS * FOURD * 2;          // 32 MiB
    float*          kvbuf = (float*)ws;          ws += (size_t)B_ * H_ * 8192 * 4;        // 1 MiB
    unsigned short* wqb   = (unsigned short*)ws; ws += (size_t)FOURD * D_ * 2;            // 8 MiB
    unsigned short* wob   = (unsigned short*)ws; ws += (size_t)D_ * D_ * 2;               // 2 MiB
    unsigned short* xb    = (unsigned short*)ws; ws += (size_t)ROWS * D_ * 2;             // 8 MiB
    float*          part  = (float*)ws;          // 16 MiB kv partials
    unsigned short* gb    = (unsigned short*)ws; // alias: part dead before attn writes g

    dim3 blk(256);
    cast_f32_bf16<<<dim3(ROWS * D_ / 4 / 256), blk, 0, stream>>>(x, xb, ROWS * D_ / 4);
    cast_f32_bf16<<<dim3(FOURD * D_ / 4 / 256), blk, 0, stream>>>(Wqkvu, wqb, FOURD * D_ / 4);
    cast_f32_bf16<<<dim3(D_ * D_ / 4 / 256), blk, 0, stream>>>(Wout, wob, D_ * D_ / 4);

    // qkvu = x @ Wqkvu^T + b (bf16 out), silu on q,k columns
    gemm_bt_128<<<dim3(FOURD / 128, ROWS / 128), blk, 0, stream>>>(
        xb, wqb, bqkvu, qkvu, ROWS, FOURD, D_, 2 * D_);
    // KV partials + reduce
    kv_mfma<<<dim3(32 * 16), blk, 0, stream>>>(qkvu, theta, part);
    kv_reduce<<<dim3(32 * 8192 / 256), blk, 0, stream>>>(part, kvbuf);
    // o = lrpe(q) @ KV, fused LN + u gating -> g (bf16)
    attn_ln_kernel<<<dim3(ROWS / 8), blk, 0, stream>>>(qkvu, kvbuf, theta, ln_w, ln_b, gb);
    // out = g @ Wout^T + bout (128x64 tile -> 512 blocks)
    gemm_bt_64<<<dim3(D_ / 64, ROWS / 128), blk, 0, stream>>>(
        gb, wob, bout, out, ROWS, D_, D_);
}

// Round 5
// 210.111 us; speedup vs baseline: 4.1333x; 1.1071x over previous
//
#include <hip/hip_runtime.h>
#include <math.h>

#define B_ 2
#define N_ 2048
#define D_ 1024
#define H_ 16
#define DH_ 64
#define ROWS (B_*N_)      // 4096
#define FOURD (4*D_)      // 4096
#define EPS_ 1e-5f

typedef short bf16x8 __attribute__((ext_vector_type(8)));
typedef unsigned short u16x8 __attribute__((ext_vector_type(8)));
typedef float f32x4  __attribute__((ext_vector_type(4)));

typedef const __attribute__((address_space(1))) unsigned int* gp_t;
typedef __attribute__((address_space(3))) unsigned int* lp_t;

__device__ __forceinline__ unsigned short f2bf(float f) {
    unsigned int x = __float_as_uint(f);
    unsigned int r = (x + 0x7fffu + ((x >> 16) & 1u)) >> 16;   // RNE
    return (unsigned short)r;
}
__device__ __forceinline__ float bf2f(unsigned short u) {
    return __uint_as_float((unsigned int)u << 16);
}

// ---------------------------------------------------------------------------
// fused fp32 -> bf16 cast of x (4M), Wqkvu (4M), Wout (1M); i in float4 units
// ---------------------------------------------------------------------------
__global__ __launch_bounds__(256)
void cast_all(const float* __restrict__ x, const float* __restrict__ w1,
              const float* __restrict__ w2, unsigned short* __restrict__ xb,
              unsigned short* __restrict__ w1b, unsigned short* __restrict__ w2b)
{
    int i = blockIdx.x * 256 + threadIdx.x;
    const float* src; unsigned short* dst; int off;
    if (i < 1048576)      { src = x;  dst = xb;  off = i; }
    else if (i < 2097152) { src = w1; dst = w1b; off = i - 1048576; }
    else                  { src = w2; dst = w2b; off = i - 2097152; }
    float4 v = ((const float4*)src)[off];
    ushort4 o;
    o.x = f2bf(v.x); o.y = f2bf(v.y); o.z = f2bf(v.z); o.w = f2bf(v.w);
    ((ushort4*)dst)[off] = o;
}

// ---------------------------------------------------------------------------
// bf16 MFMA GEMM, 128x128 tile, BK=64, XOR-swizzled LDS (conflict-free
// ds_read_b128 without breaking global_load_lds's lane-linear dest):
// LDS[row][slot] holds global k-chunk (slot ^ (row&7)), chunks of 8 bf16.
// bf16 out, silu (columns < siluLim) via __expf.
// ---------------------------------------------------------------------------
__global__ __launch_bounds__(256)
void gemm_bt_128(const unsigned short* __restrict__ A,
                 const unsigned short* __restrict__ Bw,
                 const float* __restrict__ bias, unsigned short* __restrict__ C,
                 int M, int N, int K, int siluLim)
{
    __shared__ unsigned short As[128 * 64];
    __shared__ unsigned short Bs[128 * 64];

    const int tid  = threadIdx.x;
    const int row0 = blockIdx.y * 128;
    const int col0 = blockIdx.x * 128;
    const int wave = tid >> 6;
    const int lane = tid & 63;
    const int wr   = (wave >> 1) * 64;
    const int wc   = (wave & 1) * 64;
    const int l15  = lane & 15;
    const int quad = lane >> 4;
    const int xr   = l15 & 7;            // read-side xor key (row&7 == l15&7)

    f32x4 acc[4][4] = {};

    // staging: thread -> (row = tid>>3 + 32s, slot = tid&7); source chunk = slot^ (row&7)
    const int srow = tid >> 3;
    const int skk  = ((tid & 7) ^ (srow & 7)) * 8;
    const unsigned short* ag = A  + (size_t)(row0 + srow) * K + skk;
    const unsigned short* bg = Bw + (size_t)(col0 + srow) * K + skk;
    lp_t asd = (lp_t)(void*)&As[tid * 8];
    lp_t bsd = (lp_t)(void*)&Bs[tid * 8];

    for (int k0 = 0; k0 < K; k0 += 64) {
#pragma unroll
        for (int s = 0; s < 4; ++s) {
            __builtin_amdgcn_global_load_lds((gp_t)(const void*)(ag + (size_t)(32 * s) * K + k0), asd + s * 1024, 16, 0, 0);
            __builtin_amdgcn_global_load_lds((gp_t)(const void*)(bg + (size_t)(32 * s) * K + k0), bsd + s * 1024, 16, 0, 0);
        }
        __syncthreads();

#pragma unroll
        for (int ksub = 0; ksub < 2; ++ksub) {
            const int slot = ((ksub * 4 + quad) ^ xr) * 8;
            bf16x8 af[4], bfr[4];
#pragma unroll
            for (int i = 0; i < 4; ++i)
                af[i] = *(const bf16x8*)&As[(wr + i * 16 + l15) * 64 + slot];
#pragma unroll
            for (int j = 0; j < 4; ++j)
                bfr[j] = *(const bf16x8*)&Bs[(wc + j * 16 + l15) * 64 + slot];
#pragma unroll
            for (int i = 0; i < 4; ++i)
#pragma unroll
                for (int j = 0; j < 4; ++j)
                    acc[i][j] = __builtin_amdgcn_mfma_f32_16x16x32_bf16(af[i], bfr[j], acc[i][j], 0, 0, 0);
        }
        __syncthreads();
    }

#pragma unroll
    for (int i = 0; i < 4; ++i) {
        const int r0 = row0 + wr + i * 16 + quad * 4;
#pragma unroll
        for (int j = 0; j < 4; ++j) {
            const int c = col0 + wc + j * 16 + l15;
            const float bb = bias[c];
#pragma unroll
            for (int r = 0; r < 4; ++r) {
                float v = acc[i][j][r] + bb;
                if (c < siluLim) v = v / (1.f + __expf(-v));   // silu (HW exp)
                C[(size_t)(r0 + r) * N + c] = f2bf(v);
            }
        }
    }
}

// ---------------------------------------------------------------------------
// bf16 MFMA GEMM, 128x64 tile, BK=64, same swizzle; fp32 out. 4 waves stacked
// in rows (wave w owns rows [32w, 32w+32)).
// ---------------------------------------------------------------------------
__global__ __launch_bounds__(256)
void gemm_bt_64(const unsigned short* __restrict__ A,
                const unsigned short* __restrict__ Bw,
                const float* __restrict__ bias, float* __restrict__ C,
                int M, int N, int K)
{
    __shared__ unsigned short As[128 * 64];
    __shared__ unsigned short Bs[64 * 64];

    const int tid  = threadIdx.x;
    const int row0 = blockIdx.y * 128;
    const int col0 = blockIdx.x * 64;
    const int wave = tid >> 6;
    const int lane = tid & 63;
    const int wr   = wave * 32;
    const int l15  = lane & 15;
    const int quad = lane >> 4;
    const int xr   = l15 & 7;

    f32x4 acc[2][4] = {};

    const int srow = tid >> 3;
    const int skk  = ((tid & 7) ^ (srow & 7)) * 8;
    const unsigned short* ag = A  + (size_t)(row0 + srow) * K + skk;
    const unsigned short* bg = Bw + (size_t)(col0 + srow) * K + skk;
    lp_t asd = (lp_t)(void*)&As[tid * 8];
    lp_t bsd = (lp_t)(void*)&Bs[tid * 8];

    for (int k0 = 0; k0 < K; k0 += 64) {
#pragma unroll
        for (int s = 0; s < 4; ++s)
            __builtin_amdgcn_global_load_lds((gp_t)(const void*)(ag + (size_t)(32 * s) * K + k0), asd + s * 1024, 16, 0, 0);
#pragma unroll
        for (int s = 0; s < 2; ++s)
            __builtin_amdgcn_global_load_lds((gp_t)(const void*)(bg + (size_t)(32 * s) * K + k0), bsd + s * 1024, 16, 0, 0);
        __syncthreads();

#pragma unroll
        for (int ksub = 0; ksub < 2; ++ksub) {
            const int slot = ((ksub * 4 + quad) ^ xr) * 8;
            bf16x8 af[2], bfr[4];
#pragma unroll
            for (int i = 0; i < 2; ++i)
                af[i] = *(const bf16x8*)&As[(wr + i * 16 + l15) * 64 + slot];
#pragma unroll
            for (int j = 0; j < 4; ++j)
                bfr[j] = *(const bf16x8*)&Bs[(j * 16 + l15) * 64 + slot];
#pragma unroll
            for (int i = 0; i < 2; ++i)
#pragma unroll
                for (int j = 0; j < 4; ++j)
                    acc[i][j] = __builtin_amdgcn_mfma_f32_16x16x32_bf16(af[i], bfr[j], acc[i][j], 0, 0, 0);
        }
        __syncthreads();
    }

#pragma unroll
    for (int i = 0; i < 2; ++i) {
        const int r0 = row0 + wr + i * 16 + quad * 4;
#pragma unroll
        for (int j = 0; j < 4; ++j) {
            const int c = col0 + j * 16 + l15;
            const float bb = bias[c];
#pragma unroll
            for (int r = 0; r < 4; ++r)
                C[(size_t)(r0 + r) * N + c] = acc[i][j][r] + bb;
        }
    }
}

// ---------------------------------------------------------------------------
// kv_mfma: per (b,h): partial KV[128 d, 64 e] over a 128-n chunk via MFMA.
// __sincosf (HW sin/cos of the same fp32 product the reference rounds to).
// ---------------------------------------------------------------------------
__global__ __launch_bounds__(256)
void kv_mfma(const unsigned short* __restrict__ qkvu, const float* __restrict__ theta,
             float* __restrict__ part)
{
    __shared__ unsigned short kl_s[128][136];  // [d][n], pad 8
    __shared__ unsigned short v_s [64][136];   // [e][n]

    const int bid   = blockIdx.x;
    const int chunk = bid & 15;
    const int bh    = bid >> 4;
    const int h     = bh & 15;
    const int b     = bh >> 4;
    const int tid   = threadIdx.x;
    const int lane  = tid & 63;
    const int wave  = tid >> 6;
    const int l15   = lane & 15;
    const int quad  = lane >> 4;
    const int n0    = chunk * 128;

    for (int i = tid; i < 1024; i += 256) {
        const int nn  = i >> 3;
        const int dh0 = (i & 7) * 8;
        const int n   = n0 + nn;
        const unsigned short* qrow = qkvu + (size_t)(b * N_ + n) * FOURD;
        u16x8 k8 = *(const u16x8*)(qrow + D_     + h * DH_ + dh0);
        u16x8 v8 = *(const u16x8*)(qrow + 2 * D_ + h * DH_ + dh0);
#pragma unroll
        for (int j = 0; j < 8; ++j) {
            const int dh = dh0 + j;
            const float kf = bf2f(k8[j]);
            float s, c; __sincosf(theta[h * DH_ + dh] * (float)n, &s, &c);
            kl_s[dh][nn]      = f2bf(kf * c);
            kl_s[64 + dh][nn] = f2bf(kf * s);
            v_s[dh][nn]       = v8[j];
        }
    }
    __syncthreads();

    f32x4 acc[2][4] = {};
#pragma unroll
    for (int ks = 0; ks < 4; ++ks) {
        bf16x8 a0 = *(const bf16x8*)&kl_s[wave * 32 +      l15][ks * 32 + quad * 8];
        bf16x8 a1 = *(const bf16x8*)&kl_s[wave * 32 + 16 + l15][ks * 32 + quad * 8];
#pragma unroll
        for (int j = 0; j < 4; ++j) {
            bf16x8 bfr = *(const bf16x8*)&v_s[j * 16 + l15][ks * 32 + quad * 8];
            acc[0][j] = __builtin_amdgcn_mfma_f32_16x16x32_bf16(a0, bfr, acc[0][j], 0, 0, 0);
            acc[1][j] = __builtin_amdgcn_mfma_f32_16x16x32_bf16(a1, bfr, acc[1][j], 0, 0, 0);
        }
    }

    float* pp = part + ((size_t)bh * 16 + chunk) * 8192;
#pragma unroll
    for (int i = 0; i < 2; ++i) {
        const int d0 = wave * 32 + i * 16 + quad * 4;
#pragma unroll
        for (int j = 0; j < 4; ++j) {
            const int e = j * 16 + l15;
#pragma unroll
            for (int r = 0; r < 4; ++r)
                pp[(d0 + r) * 64 + e] = acc[i][j][r];
        }
    }
}

// ---------------------------------------------------------------------------
// kv_reduce: kv[bh][i] = sum over 16 chunk partials.
// ---------------------------------------------------------------------------
__global__ __launch_bounds__(256)
void kv_reduce(const float* __restrict__ part, float* __restrict__ kv)
{
    const int i  = blockIdx.x * 256 + threadIdx.x;
    const int bh = i >> 13;
    const float* pp = part + ((size_t)bh * 16) * 8192 + (i & 8191);
    float s = 0.f;
#pragma unroll
    for (int c = 0; c < 16; ++c) s += pp[c * 8192];
    kv[i] = s;
}

// ---------------------------------------------------------------------------
// attn_ln: 8 rows per block. o = lrpe(q) @ KV (fp32), fused LayerNorm +
// u gating, bf16 output.
// ---------------------------------------------------------------------------
__global__ __launch_bounds__(256)
void attn_ln_kernel(const unsigned short* __restrict__ qkvu, const float* __restrict__ kvb,
                    const float* __restrict__ theta, const float* __restrict__ ln_w,
                    const float* __restrict__ ln_b, unsigned short* __restrict__ g)
{
    __shared__ float qc_s[8][1024];
    __shared__ float qs_s[8][1024];
    __shared__ float red[4][16];
    __shared__ float mured[8], rsred[8];

    const int row0 = blockIdx.x * 8;
    const int b    = row0 >> 11;
    const int tid  = threadIdx.x;
    const int lane = tid & 63;
    const int wave = tid >> 6;

    for (int i = tid; i < 2048; i += 256) {
        const int r  = i >> 8;
        const int c0 = (i & 255) * 4;
        const int n  = (row0 + r) & (N_ - 1);
        ushort4 qv = *(const ushort4*)&qkvu[(size_t)(row0 + r) * FOURD + c0];
        float4 tv = *(const float4*)&theta[c0];
        float q[4] = {bf2f(qv.x), bf2f(qv.y), bf2f(qv.z), bf2f(qv.w)};
        float t[4] = {tv.x, tv.y, tv.z, tv.w};
        float4 cv, sv;
        float* cp = (float*)&cv; float* sp = (float*)&sv;
#pragma unroll
        for (int j = 0; j < 4; ++j) {
            float s, c; __sincosf(t[j] * (float)n, &s, &c);
            cp[j] = q[j] * c; sp[j] = q[j] * s;
        }
        *(float4*)&qc_s[r][c0] = cv;
        *(float4*)&qs_s[r][c0] = sv;
    }
    __syncthreads();

    const int c0 = tid * 4;
    const int h  = c0 >> 6;
    const int e0 = c0 & 63;
    const float* kvp = kvb + (size_t)(b * H_ + h) * 8192;

    float o[8][4] = {};
    for (int d = 0; d < 64; ++d) {
        float4 kc = *(const float4*)&kvp[d * 64 + e0];
        float4 ks = *(const float4*)&kvp[(64 + d) * 64 + e0];
#pragma unroll
        for (int r = 0; r < 8; ++r) {
            const float qc = qc_s[r][h * 64 + d];
            const float qs = qs_s[r][h * 64 + d];
            o[r][0] = fmaf(qc, kc.x, fmaf(qs, ks.x, o[r][0]));
            o[r][1] = fmaf(qc, kc.y, fmaf(qs, ks.y, o[r][1]));
            o[r][2] = fmaf(qc, kc.z, fmaf(qs, ks.z, o[r][2]));
            o[r][3] = fmaf(qc, kc.w, fmaf(qs, ks.w, o[r][3]));
        }
    }

    float sum[8], sq[8];
#pragma unroll
    for (int r = 0; r < 8; ++r) {
        sum[r] = o[r][0] + o[r][1] + o[r][2] + o[r][3];
        sq[r]  = o[r][0]*o[r][0] + o[r][1]*o[r][1] + o[r][2]*o[r][2] + o[r][3]*o[r][3];
    }
#pragma unroll
    for (int off = 32; off; off >>= 1)
#pragma unroll
        for (int r = 0; r < 8; ++r) {
            sum[r] += __shfl_down(sum[r], off, 64);
            sq[r]  += __shfl_down(sq[r],  off, 64);
        }
    if (lane == 0)
#pragma unroll
        for (int r = 0; r < 8; ++r) { red[wave][r] = sum[r]; red[wave][8 + r] = sq[r]; }
    __syncthreads();
    if (tid < 8) {
        const float s  = red[0][tid] + red[1][tid] + red[2][tid] + red[3][tid];
        const float q2 = red[0][8+tid] + red[1][8+tid] + red[2][8+tid] + red[3][8+tid];
        const float mu = s * (1.f / (float)D_);
        const float var = q2 * (1.f / (float)D_) - mu * mu;
        mured[tid] = mu;
        rsred[tid] = rsqrtf(var + EPS_);
    }
    __syncthreads();

    float4 wv = *(const float4*)&ln_w[c0];
    float4 bv = *(const float4*)&ln_b[c0];
#pragma unroll
    for (int r = 0; r < 8; ++r) {
        ushort4 uvb = *(const ushort4*)&qkvu[(size_t)(row0 + r) * FOURD + 3 * D_ + c0];
        const float mu = mured[r], rs = rsred[r];
        ushort4 ov;
        ov.x = f2bf(((o[r][0] - mu) * rs * wv.x + bv.x) * bf2f(uvb.x));
        ov.y = f2bf(((o[r][1] - mu) * rs * wv.y + bv.y) * bf2f(uvb.y));
        ov.z = f2bf(((o[r][2] - mu) * rs * wv.z + bv.z) * bf2f(uvb.z));
        ov.w = f2bf(((o[r][3] - mu) * rs * wv.w + bv.w) * bf2f(uvb.w));
        *(ushort4*)&g[(size_t)(row0 + r) * D_ + c0] = ov;
    }
}

// ---------------------------------------------------------------------------
extern "C" void kernel_launch(void* const* d_in, const int* in_sizes, int n_in,
                              void* d_out, int out_size, void* d_ws, size_t ws_size,
                              hipStream_t stream)
{
    const float* x     = (const float*)d_in[0];
    const float* Wqkvu = (const float*)d_in[2];
    const float* bqkvu = (const float*)d_in[3];
    const float* Wout  = (const float*)d_in[4];
    const float* bout  = (const float*)d_in[5];
    const float* theta = (const float*)d_in[6];
    const float* ln_w  = (const float*)d_in[7];
    const float* ln_b  = (const float*)d_in[8];
    float* out = (float*)d_out;

    // workspace layout
    char* ws = (char*)d_ws;
    unsigned short* qkvu  = (unsigned short*)ws; ws += (size_t)ROWS * FOURD * 2;          // 32 MiB
    float*          kvbuf = (float*)ws;          ws += (size_t)B_ * H_ * 8192 * 4;        // 1 MiB
    unsigned short* wqb   = (unsigned short*)ws; ws += (size_t)FOURD * D_ * 2;            // 8 MiB
    unsigned short* wob   = (unsigned short*)ws; ws += (size_t)D_ * D_ * 2;               // 2 MiB
    unsigned short* xb    = (unsigned short*)ws; ws += (size_t)ROWS * D_ * 2;             // 8 MiB
    float*          part  = (float*)ws;          // 16 MiB kv partials
    unsigned short* gb    = (unsigned short*)ws; // alias: part dead before attn writes g

    dim3 blk(256);
    // fused casts: (4M + 4M + 1M)/4 float4s = 2359296 threads
    cast_all<<<dim3(2359296 / 256), blk, 0, stream>>>(x, Wqkvu, Wout, xb, wqb, wob);

    // qkvu = x @ Wqkvu^T + b (bf16 out), silu on q,k columns
    gemm_bt_128<<<dim3(FOURD / 128, ROWS / 128), blk, 0, stream>>>(
        xb, wqb, bqkvu, qkvu, ROWS, FOURD, D_, 2 * D_);
    // KV partials + reduce
    kv_mfma<<<dim3(32 * 16), blk, 0, stream>>>(qkvu, theta, part);
    kv_reduce<<<dim3(32 * 8192 / 256), blk, 0, stream>>>(part, kvbuf);
    // o = lrpe(q) @ KV, fused LN + u gating -> g (bf16)
    attn_ln_kernel<<<dim3(ROWS / 8), blk, 0, stream>>>(qkvu, kvbuf, theta, ln_w, ln_b, gb);
    // out = g @ Wout^T + bout (128x64 tile -> 512 blocks)
    gemm_bt_64<<<dim3(D_ / 64, ROWS / 128), blk, 0, stream>>>(
        gb, wob, bout, out, ROWS, D_, D_);
}